// Round 1
// baseline (2587.272 us; speedup 1.0000x reference)
//
#include <hip/hip_runtime.h>
#include <hip/hip_bf16.h>
#include <math.h>

// Problem constants
#define U_   300
#define K_   19
#define FC_  100
#define B_   256
#define L_   1000
#define P_   140     // pooled length: windows l = 7p .. 7p+6, p < 140 (l <= 979)
#define EPS_ 1e-5f
#define UB_  30      // units per block in stage 1

// ---------------------------------------------------------------------------
// Stage 1: conv(4->300,K=19) + BN1 + maxpool(7,7) + exp  -> pooled (B,U,P)
// Block: 256 threads, handles (one batch b, 30 units).
// Each thread c<245 owns l in [4c, 4c+3]; x window (22 float4) lives in regs.
// Weights/BN params read via block-uniform indices -> scalar loads.
// exp(max(...)) == max over affine values, then one exp (exp is monotone).
// ---------------------------------------------------------------------------
__global__ __launch_bounds__(256, 4)
void conv_pool_k(const float4* __restrict__ x4,      // (B, L) as float4 over D=4
                 const float* __restrict__ w_conv,   // (U, 4, 19)
                 const float* __restrict__ b_conv,
                 const float* __restrict__ g1,
                 const float* __restrict__ be1,
                 const float* __restrict__ m1,
                 const float* __restrict__ v1,
                 float* __restrict__ pooled)         // (B, U, P)
{
    __shared__ float4 xs[1000];
    __shared__ float  ybuf[980];
    const int tid = threadIdx.x;
    const int b   = blockIdx.y;
    const int u0  = blockIdx.x * UB_;

    for (int i = tid; i < 1000; i += 256) xs[i] = x4[b * 1000 + i];
    __syncthreads();

    // register-resident sliding window: l = 4c .. 4c+3, need x4[4c .. 4c+21]
    float4 xw[22];
    const int c = tid;
    if (c < 245) {
#pragma unroll
        for (int j = 0; j < 22; ++j) xw[j] = xs[4 * c + j];
    }

    for (int uu = 0; uu < UB_; ++uu) {
        const int u = u0 + uu;
        const float s1 = g1[u] * (1.0f / sqrtf(v1[u] + EPS_));
        const float o1 = (b_conv[u] - m1[u]) * s1 + be1[u];
        const float* __restrict__ w = w_conv + u * (4 * K_);

        float a[4] = {0.f, 0.f, 0.f, 0.f};
        if (c < 245) {
#pragma unroll
            for (int k = 0; k < K_; ++k) {
                const float w0 = w[k];
                const float w1 = w[K_ + k];
                const float w2 = w[2 * K_ + k];
                const float w3 = w[3 * K_ + k];
#pragma unroll
                for (int t = 0; t < 4; ++t) {
                    const float4 xv = xw[k + t];
                    a[t] = fmaf(xv.x, w0, a[t]);
                    a[t] = fmaf(xv.y, w1, a[t]);
                    a[t] = fmaf(xv.z, w2, a[t]);
                    a[t] = fmaf(xv.w, w3, a[t]);
                }
            }
            *(float4*)&ybuf[4 * c] = make_float4(fmaf(a[0], s1, o1),
                                                 fmaf(a[1], s1, o1),
                                                 fmaf(a[2], s1, o1),
                                                 fmaf(a[3], s1, o1));
        }
        __syncthreads();

        if (tid < P_) {
            const float* yb = &ybuf[7 * tid];   // stride 7 vs 32 banks: conflict-free
            float m = yb[0];
#pragma unroll
            for (int t = 1; t < 7; ++t) m = fmaxf(m, yb[t]);
            pooled[(b * U_ + u) * P_ + tid] = __expf(m);
        }
        __syncthreads();   // protect ybuf before next unit overwrites it
    }
}

// ---------------------------------------------------------------------------
// Stage 2: per-unit FC1(140->100)+BN2+ReLU, FC2(100->1)+BN3+ReLU -> z (B,U)
// Block: 256 threads = 64 batches x 4 f-quarters; one unit per block.
// Pooled tile (64x140) in LDS; w_fc1 rows streamed (broadcast, L2-resident).
// ---------------------------------------------------------------------------
__global__ __launch_bounds__(256, 4)
void fc_k(const float* __restrict__ pooled,   // (B,U,P)
          const float* __restrict__ w_fc1,    // (U,FC,P)
          const float* __restrict__ b_fc1,    // (U,FC)
          const float* __restrict__ g2,
          const float* __restrict__ be2,
          const float* __restrict__ m2,
          const float* __restrict__ v2,
          const float* __restrict__ w_fc2,    // (U,FC)
          const float* __restrict__ b_fc2,
          const float* __restrict__ g3,
          const float* __restrict__ be3,
          const float* __restrict__ m3,
          const float* __restrict__ v3,
          float* __restrict__ zbuf)           // (B, 304) padded
{
    __shared__ float4 ps[64 * 35];            // 64 batches x 140 floats
    const int tid = threadIdx.x;
    const int u   = blockIdx.y;
    const int bt  = blockIdx.x;

    const float4* pooled4 = (const float4*)pooled;
    for (int i = tid; i < 64 * 35; i += 256) {
        const int bl = i / 35, j = i % 35;
        ps[i] = pooled4[((bt * 64 + bl) * U_ + u) * 35 + j];
    }
    __syncthreads();

    const int fq = tid & 3;        // f-quarter: owns f = fq*25 .. fq*25+24
    const int bl = tid >> 2;       // local batch

    float acc[25];
#pragma unroll
    for (int f = 0; f < 25; ++f) acc[f] = 0.f;

    const float4* __restrict__ wbase = (const float4*)w_fc1 + (u * FC_ + fq * 25) * 35;
    const float4* prow = &ps[bl * 35];

    for (int j = 0; j < 35; ++j) {
        const float4 pv = prow[j];
#pragma unroll
        for (int f = 0; f < 25; ++f) {
            const float4 wv = wbase[f * 35 + j];
            acc[f] = fmaf(pv.x, wv.x, acc[f]);
            acc[f] = fmaf(pv.y, wv.y, acc[f]);
            acc[f] = fmaf(pv.z, wv.z, acc[f]);
            acc[f] = fmaf(pv.w, wv.w, acc[f]);
        }
    }

    // BN2 + ReLU + FC2 partial
    float zp = 0.f;
    const int fbase = u * FC_ + fq * 25;
#pragma unroll
    for (int f = 0; f < 25; ++f) {
        const int fg = fbase + f;
        const float s2 = g2[fg] * (1.0f / sqrtf(v2[fg] + EPS_));
        const float o2 = (b_fc1[fg] - m2[fg]) * s2 + be2[fg];
        float h = fmaf(acc[f], s2, o2);
        h = fmaxf(h, 0.f);
        zp = fmaf(h, w_fc2[fg], zp);
    }
    // reduce across the 4 f-quarters (lanes differ in bits 0..1)
    zp += __shfl_xor(zp, 1);
    zp += __shfl_xor(zp, 2);

    if (fq == 0) {
        const float s3 = g3[u] * (1.0f / sqrtf(v3[u] + EPS_));
        const float o3 = (b_fc2[u] - m3[u]) * s3 + be3[u];
        const float z = fmaxf(fmaf(zp, s3, o3), 0.f);
        zbuf[(bt * 64 + bl) * 304 + u] = z;
    }
}

// ---------------------------------------------------------------------------
// Stage 3: out[b] = sigmoid( sum_u z[b,u] * w_out[u] + b_out )
// ---------------------------------------------------------------------------
__global__ __launch_bounds__(320, 2)
void out_k(const float* __restrict__ zbuf,
           const float* __restrict__ w_out,    // (U,1)
           const float* __restrict__ b_out,    // (1,)
           float* __restrict__ out)            // (B,1)
{
    __shared__ float red[5];
    const int tid = threadIdx.x;
    const int b   = blockIdx.x;

    float v = 0.f;
    if (tid < U_) v = zbuf[b * 304 + tid] * w_out[tid];
#pragma unroll
    for (int o = 32; o > 0; o >>= 1) v += __shfl_xor(v, o);
    if ((tid & 63) == 0) red[tid >> 6] = v;
    __syncthreads();
    if (tid == 0) {
        const float s = red[0] + red[1] + red[2] + red[3] + red[4] + b_out[0];
        out[b] = 1.0f / (1.0f + __expf(-s));
    }
}

// ---------------------------------------------------------------------------
extern "C" void kernel_launch(void* const* d_in, const int* in_sizes, int n_in,
                              void* d_out, int out_size, void* d_ws, size_t ws_size,
                              hipStream_t stream)
{
    const float* input_seq = (const float*)d_in[0];   // (B,L,4)
    const float* w_conv    = (const float*)d_in[1];
    const float* b_conv    = (const float*)d_in[2];
    const float* g1        = (const float*)d_in[3];
    const float* be1       = (const float*)d_in[4];
    const float* m1        = (const float*)d_in[5];
    const float* v1        = (const float*)d_in[6];
    const float* w_fc1     = (const float*)d_in[7];
    const float* b_fc1     = (const float*)d_in[8];
    const float* g2        = (const float*)d_in[9];
    const float* be2       = (const float*)d_in[10];
    const float* m2        = (const float*)d_in[11];
    const float* v2        = (const float*)d_in[12];
    const float* w_fc2     = (const float*)d_in[13];
    const float* b_fc2     = (const float*)d_in[14];
    const float* g3        = (const float*)d_in[15];
    const float* be3       = (const float*)d_in[16];
    const float* m3        = (const float*)d_in[17];
    const float* v3        = (const float*)d_in[18];
    const float* w_out     = (const float*)d_in[19];
    const float* b_out     = (const float*)d_in[20];

    float* pooled = (float*)d_ws;                                   // B*U*P f32 = 43.0 MB
    float* zbuf   = (float*)((char*)d_ws + (size_t)B_ * U_ * P_ * sizeof(float)); // B*304 f32

    conv_pool_k<<<dim3(U_ / UB_, B_), 256, 0, stream>>>(
        (const float4*)input_seq, w_conv, b_conv, g1, be1, m1, v1, pooled);

    fc_k<<<dim3(B_ / 64, U_), 256, 0, stream>>>(
        pooled, w_fc1, b_fc1, g2, be2, m2, v2, w_fc2, b_fc2, g3, be3, m3, v3, zbuf);

    out_k<<<dim3(B_), 320, 0, stream>>>(zbuf, w_out, b_out, (float*)d_out);
}

// Round 2
// 663.598 us; speedup vs baseline: 3.8989x; 3.8989x over previous
//
#include <hip/hip_runtime.h>
#include <hip/hip_bf16.h>
#include <math.h>

// Problem constants
#define U_   300
#define K_   19
#define FC_  100
#define B_   256
#define L_   1000
#define P_   140     // pooled length: windows l = 7p .. 7p+6, p < 140 (l <= 979)
#define EPS_ 1e-5f
#define UB_  30      // units per block in stage 1

// LDS padding for xs: phys(i) = i + (i>>2)  -> lane float4-stride 5 (odd),
// so wave b128 reads tile all 32 banks instead of 8.
__device__ __forceinline__ int xpad(int i) { return i + (i >> 2); }

// ---------------------------------------------------------------------------
// Stage 1: conv(4->300,K=19) + BN1 + maxpool(7,7) + exp  -> pooled (B,U,P)
// Block: 256 threads = (one batch b, 30 units as 15 pairs).
// Thread c<245 owns outputs l in [4c,4c+3]; sliding window lives in a
// 4-register rotating buffer (static indices after unroll -> no spill),
// re-read from LDS per unit-PAIR (2 units share each window load).
// exp(max(..)) == exp of max (exp monotone) -> one __expf per pooled output.
// ---------------------------------------------------------------------------
__global__ __launch_bounds__(256, 4)
void conv_pool_k(const float4* __restrict__ x4,      // (B, L) as float4 over D=4
                 const float* __restrict__ w_conv,   // (U, 4, 19)
                 const float* __restrict__ b_conv,
                 const float* __restrict__ g1,
                 const float* __restrict__ be1,
                 const float* __restrict__ m1,
                 const float* __restrict__ v1,
                 float* __restrict__ pooled)         // (B, U, P)
{
    __shared__ float4 xs[1250];                      // padded 1000 -> 1250
    __shared__ float  ybuf[2][980];
    const int tid = threadIdx.x;
    const int b   = blockIdx.y;
    const int u0  = blockIdx.x * UB_;

    for (int i = tid; i < 1000; i += 256) xs[xpad(i)] = x4[b * 1000 + i];
    __syncthreads();

    const int c = tid;
    const float4* __restrict__ xp = &xs[5 * c];      // phys(4c) = 5c

    for (int uu = 0; uu < UB_; uu += 2) {
        const int u = u0 + uu;
        const float s1A = g1[u]     / sqrtf(v1[u]     + EPS_);
        const float o1A = (b_conv[u]     - m1[u]    ) * s1A + be1[u];
        const float s1B = g1[u + 1] / sqrtf(v1[u + 1] + EPS_);
        const float o1B = (b_conv[u + 1] - m1[u + 1]) * s1B + be1[u + 1];
        const float* __restrict__ wA = w_conv + u * 76;
        const float* __restrict__ wB = wA + 76;

        if (c < 245) {
            // rotating window r[(k+t)&3]; offsets phys(4c+j)-phys(4c)=j+(j>>2)
            float4 r[4];
            r[0] = xp[0]; r[1] = xp[1]; r[2] = xp[2]; r[3] = xp[3];
            float aA[4] = {0.f, 0.f, 0.f, 0.f};
            float aB[4] = {0.f, 0.f, 0.f, 0.f};
#pragma unroll
            for (int k = 0; k < K_; ++k) {
                const float wa0 = wA[k],      wb0 = wB[k];
                const float wa1 = wA[19 + k], wb1 = wB[19 + k];
                const float wa2 = wA[38 + k], wb2 = wB[38 + k];
                const float wa3 = wA[57 + k], wb3 = wB[57 + k];
#pragma unroll
                for (int t = 0; t < 4; ++t) {
                    const float4 xv = r[(k + t) & 3];
                    aA[t] = fmaf(xv.x, wa0, aA[t]);
                    aA[t] = fmaf(xv.y, wa1, aA[t]);
                    aA[t] = fmaf(xv.z, wa2, aA[t]);
                    aA[t] = fmaf(xv.w, wa3, aA[t]);
                    aB[t] = fmaf(xv.x, wb0, aB[t]);
                    aB[t] = fmaf(xv.y, wb1, aB[t]);
                    aB[t] = fmaf(xv.z, wb2, aB[t]);
                    aB[t] = fmaf(xv.w, wb3, aB[t]);
                }
                if (k < K_ - 1) {
                    const int j = k + 4;
                    r[k & 3] = xp[j + (j >> 2)];
                }
            }
            ybuf[0][4 * c + 0] = fmaf(aA[0], s1A, o1A);
            ybuf[0][4 * c + 1] = fmaf(aA[1], s1A, o1A);
            ybuf[0][4 * c + 2] = fmaf(aA[2], s1A, o1A);
            ybuf[0][4 * c + 3] = fmaf(aA[3], s1A, o1A);
            ybuf[1][4 * c + 0] = fmaf(aB[0], s1B, o1B);
            ybuf[1][4 * c + 1] = fmaf(aB[1], s1B, o1B);
            ybuf[1][4 * c + 2] = fmaf(aB[2], s1B, o1B);
            ybuf[1][4 * c + 3] = fmaf(aB[3], s1B, o1B);
        }
        __syncthreads();

        // pool both units: 280 outputs, stride-7 scalar reads (7 coprime 32)
        for (int pp = tid; pp < 2 * P_; pp += 256) {
            const int which = (pp >= P_) ? 1 : 0;
            const int p = pp - which * P_;
            const float* yb = &ybuf[which][7 * p];
            float m = yb[0];
#pragma unroll
            for (int t = 1; t < 7; ++t) m = fmaxf(m, yb[t]);
            pooled[((size_t)b * U_ + (u + which)) * P_ + p] = __expf(m);
        }
        __syncthreads();   // protect ybuf before next pair overwrites it
    }
}

// ---------------------------------------------------------------------------
// Stage 2: per-unit FC1(140->100)+BN2+ReLU, FC2(100->1)+BN3+ReLU -> z (B,U)
// Block: 256 threads = 64 batches x 4 f-quarters; one (unit, batch-tile).
// f processed in chunks of 5 (acc[5] cannot spill). Pooled tile in LDS,
// broadcast reads; w_fc1 rows broadcast from L2/L3.
// ---------------------------------------------------------------------------
__global__ __launch_bounds__(256, 4)
void fc_k(const float* __restrict__ pooled,   // (B,U,P)
          const float* __restrict__ w_fc1,    // (U,FC,P)
          const float* __restrict__ b_fc1,    // (U,FC)
          const float* __restrict__ g2,
          const float* __restrict__ be2,
          const float* __restrict__ m2,
          const float* __restrict__ v2,
          const float* __restrict__ w_fc2,    // (U,FC)
          const float* __restrict__ b_fc2,
          const float* __restrict__ g3,
          const float* __restrict__ be3,
          const float* __restrict__ m3,
          const float* __restrict__ v3,
          float* __restrict__ zbuf)           // (B, 304) padded
{
    __shared__ float4 ps[64 * 35];            // 64 batches x 140 floats
    const int tid = threadIdx.x;
    const int u   = blockIdx.y;
    const int bt  = blockIdx.x;

    const float4* pooled4 = (const float4*)pooled;
    for (int i = tid; i < 64 * 35; i += 256) {
        const int bl = i / 35, j = i - bl * 35;
        ps[i] = pooled4[(((size_t)bt * 64 + bl) * U_ + u) * 35 + j];
    }
    __syncthreads();

    const int fq = tid & 3;        // f-quarter: owns f = fq*25 .. fq*25+24
    const int bl = tid >> 2;       // local batch
    const float4* __restrict__ prow = &ps[bl * 35];

    float zp = 0.f;
    const int fbase0 = u * FC_ + fq * 25;

    for (int ch = 0; ch < 5; ++ch) {
        const int f0 = fbase0 + ch * 5;                     // global f row base
        const float4* __restrict__ wb = (const float4*)w_fc1 + (size_t)f0 * 35;
        float acc[5] = {0.f, 0.f, 0.f, 0.f, 0.f};
        for (int j = 0; j < 35; ++j) {
            const float4 pv = prow[j];
#pragma unroll
            for (int f = 0; f < 5; ++f) {
                const float4 wv = wb[f * 35 + j];
                acc[f] = fmaf(pv.x, wv.x, acc[f]);
                acc[f] = fmaf(pv.y, wv.y, acc[f]);
                acc[f] = fmaf(pv.z, wv.z, acc[f]);
                acc[f] = fmaf(pv.w, wv.w, acc[f]);
            }
        }
#pragma unroll
        for (int f = 0; f < 5; ++f) {
            const int fg = f0 + f;
            const float s2 = g2[fg] / sqrtf(v2[fg] + EPS_);
            const float o2 = (b_fc1[fg] - m2[fg]) * s2 + be2[fg];
            const float h = fmaxf(fmaf(acc[f], s2, o2), 0.f);
            zp = fmaf(h, w_fc2[fg], zp);
        }
    }

    // reduce across the 4 f-quarters (lanes differ in bits 0..1)
    zp += __shfl_xor(zp, 1);
    zp += __shfl_xor(zp, 2);

    if (fq == 0) {
        const float s3 = g3[u] / sqrtf(v3[u] + EPS_);
        const float o3 = (b_fc2[u] - m3[u]) * s3 + be3[u];
        const float z = fmaxf(fmaf(zp, s3, o3), 0.f);
        zbuf[((size_t)bt * 64 + bl) * 304 + u] = z;
    }
}

// ---------------------------------------------------------------------------
// Stage 3: out[b] = sigmoid( sum_u z[b,u] * w_out[u] + b_out )
// ---------------------------------------------------------------------------
__global__ __launch_bounds__(320, 2)
void out_k(const float* __restrict__ zbuf,
           const float* __restrict__ w_out,    // (U,1)
           const float* __restrict__ b_out,    // (1,)
           float* __restrict__ out)            // (B,1)
{
    __shared__ float red[5];
    const int tid = threadIdx.x;
    const int b   = blockIdx.x;

    float v = 0.f;
    if (tid < U_) v = zbuf[(size_t)b * 304 + tid] * w_out[tid];
#pragma unroll
    for (int o = 32; o > 0; o >>= 1) v += __shfl_xor(v, o);
    if ((tid & 63) == 0) red[tid >> 6] = v;
    __syncthreads();
    if (tid == 0) {
        const float s = red[0] + red[1] + red[2] + red[3] + red[4] + b_out[0];
        out[b] = 1.0f / (1.0f + __expf(-s));
    }
}

// ---------------------------------------------------------------------------
extern "C" void kernel_launch(void* const* d_in, const int* in_sizes, int n_in,
                              void* d_out, int out_size, void* d_ws, size_t ws_size,
                              hipStream_t stream)
{
    const float* input_seq = (const float*)d_in[0];   // (B,L,4)
    const float* w_conv    = (const float*)d_in[1];
    const float* b_conv    = (const float*)d_in[2];
    const float* g1        = (const float*)d_in[3];
    const float* be1       = (const float*)d_in[4];
    const float* m1        = (const float*)d_in[5];
    const float* v1        = (const float*)d_in[6];
    const float* w_fc1     = (const float*)d_in[7];
    const float* b_fc1     = (const float*)d_in[8];
    const float* g2        = (const float*)d_in[9];
    const float* be2       = (const float*)d_in[10];
    const float* m2        = (const float*)d_in[11];
    const float* v2        = (const float*)d_in[12];
    const float* w_fc2     = (const float*)d_in[13];
    const float* b_fc2     = (const float*)d_in[14];
    const float* g3        = (const float*)d_in[15];
    const float* be3       = (const float*)d_in[16];
    const float* m3        = (const float*)d_in[17];
    const float* v3        = (const float*)d_in[18];
    const float* w_out     = (const float*)d_in[19];
    const float* b_out     = (const float*)d_in[20];

    float* pooled = (float*)d_ws;                                   // B*U*P f32 = 43.0 MB
    float* zbuf   = (float*)((char*)d_ws + (size_t)B_ * U_ * P_ * sizeof(float)); // B*304 f32

    conv_pool_k<<<dim3(U_ / UB_, B_), 256, 0, stream>>>(
        (const float4*)input_seq, w_conv, b_conv, g1, be1, m1, v1, pooled);

    fc_k<<<dim3(B_ / 64, U_), 256, 0, stream>>>(
        pooled, w_fc1, b_fc1, g2, be2, m2, v2, w_fc2, b_fc2, g3, be3, m3, v3, zbuf);

    out_k<<<dim3(B_), 320, 0, stream>>>(zbuf, w_out, b_out, (float*)d_out);
}